// Round 13
// baseline (290.067 us; speedup 1.0000x reference)
//
#include <hip/hip_runtime.h>
#include <math.h>

#define N_PTS 65536
#define DIM   64
#define K_CL  128
#define EPSV  1e-8f
#define CAP   8192

// ---------------- ws layout (bytes) ----------------
// 0        : fill_acc[128] float
// 1024     : pred_x[N] int            -> 263168
// 263168   : idx_x[128*CAP] int       -> 4457472
// 4457472  : idx_t[128*CAP] int       -> 8651776
// 8651776  : count_x[128], +512: count_t[128]
// 8652800  : parts[8192] float        -> 8685568
// 8685568  : sumw[N] float            -> 8947712
// 8947712  : done int (inv_sumw region retired in R28)
// 9209856  : pred_enc[N] u64          -> 9734144
// 9734144  : offc[128] int            -> 9734656
// 9734656  : ord[128] int             -> 9735168  (cluster ids, m desc)
// 9735168  : gxT (16908288 B)         -> 26643456   } wmat (32 MB, dead after
// 26643456 : gtT (16908288 B)         -> 43551744   } k_fill) overlays these
// Session ledger:
// R19: heavy-first ord[] WIN. R20/R21: diff fusion regressed both ways
//   (k_sort tasks must stay independent). R23: front-end fusion refuted
//   (occupancy collapse). R24: gather-fused sort WIN (316->284.6, deleted
//   k_gather_t). R25/R26: XCD binding fixed FETCH (112->17MB) and LPT fixed
//   balance, but total 303 both times (L2 write-thrash hits k_diff) -- XCD
//   line closed. R27 = R24 reconfirmed (284.07, counters reproduced).
// R28: launch consolidation (9->7). k_pred deleted: k_fill computes
//   1.0f/sumw inline (same IEEE div -> bit-identical products) and its
//   j==0 blocks write pred_x from pred_enc (same bits). k_offsets deleted:
//   last-finishing k_scatter block (threadfence release + device atomicAdd
//   + acquire, G16-compliant) runs byte-identical offc/ord logic -- kills
//   the 1-block GPU-wide bubble. All downstream inputs bit-identical.

__global__ __launch_bounds__(256) void k_init(
    float* __restrict__ fill_acc, float* __restrict__ sumw,
    unsigned long long* __restrict__ pred_enc, int* __restrict__ done) {
  const int i = blockIdx.x * 256 + threadIdx.x;
  if (i < K_CL) fill_acc[i] = 0.0f;
  if (i == 0) *done = 0;
  sumw[i] = 0.0f;
  pred_enc[i] = 0xFFFFFFFFFFFFFFFFull;
}

// Block-level K-split; jbase block-uniform -> centers scalarized (s_load).
// Writes w[j][p] (coalesced) so the normalize pass needn't recompute.
__global__ __launch_bounds__(256) void k_dist1(
    const float* __restrict__ x, const float* __restrict__ centers,
    float* __restrict__ sumw, unsigned long long* __restrict__ pred_enc,
    float* __restrict__ w)
{
  __shared__ float csq[32];
  const int kb    = blockIdx.x & 3;
  const int pb    = blockIdx.x >> 2;
  const int jbase = kb << 5;
  const int tid   = threadIdx.x;
  const int p     = pb * 256 + tid;

  if (tid < 32) {
    const float* cp = centers + (jbase + tid) * DIM;
    float s = 0.0f;
    #pragma unroll 8
    for (int d = 0; d < DIM; ++d) { float v = cp[d]; s += v * v; }
    csq[tid] = s;
  }

  float xr[DIM];
  const float4* xp = reinterpret_cast<const float4*>(x + (size_t)p * DIM);
  #pragma unroll
  for (int q = 0; q < DIM / 4; ++q) {
    float4 v = xp[q];
    xr[4 * q + 0] = v.x; xr[4 * q + 1] = v.y;
    xr[4 * q + 2] = v.z; xr[4 * q + 3] = v.w;
  }
  float xsq = 0.0f;
  #pragma unroll
  for (int d = 0; d < DIM; ++d) xsq += xr[d] * xr[d];
  __syncthreads();

  float sw = 0.0f, best = INFINITY;
  int   bj = jbase;
  #pragma unroll 2
  for (int jj = 0; jj < 32; ++jj) {
    const int j = jbase + jj;
    const float* cp = centers + j * DIM;
    float d0 = 0.f, d1 = 0.f, d2a = 0.f, d3 = 0.f;
    #pragma unroll
    for (int d = 0; d < DIM; d += 4) {
      d0  += xr[d + 0] * cp[d + 0];
      d1  += xr[d + 1] * cp[d + 1];
      d2a += xr[d + 2] * cp[d + 2];
      d3  += xr[d + 3] * cp[d + 3];
    }
    float dot  = (d0 + d1) + (d2a + d3);
    float dsq  = xsq + csq[jj] - 2.0f * dot;
    float dist = sqrtf(fmaxf(dsq, 0.0f));
    float ww   = 1.0f / (dist + EPSV);
    w[(size_t)j * N_PTS + p] = ww;
    sw += ww;
    if (dist < best) { best = dist; bj = j; }
  }
  atomicAdd(&sumw[p], sw);
  const unsigned long long enc =
      ((unsigned long long)__float_as_uint(best) << 32) | (unsigned int)bj;
  atomicMin(&pred_enc[p], enc);
}

// streaming normalize+reduce: block (j, seg of 8192 points); 1 atomic/block.
// inv computed inline as 1.0f/sumw (same IEEE div bits k_pred produced);
// j==0 blocks also materialize pred_x from pred_enc (same bit extraction).
__global__ __launch_bounds__(256) void k_fill(
    const float* __restrict__ w, const float* __restrict__ sumw,
    const unsigned long long* __restrict__ pred_enc,
    int* __restrict__ pred_x, float* __restrict__ fill_acc)
{
  __shared__ float red[4];
  const int j    = blockIdx.x >> 3;
  const int seg  = blockIdx.x & 7;
  const int tid  = threadIdx.x;
  if (j == 0) {
    const int base = seg * 8192;
    #pragma unroll 4
    for (int q = 0; q < 32; ++q) {
      const int p = base + q * 256 + tid;
      pred_x[p] = (int)(pred_enc[p] & 0xFFFFFFFFull);
    }
  }
  const float4* wj = reinterpret_cast<const float4*>(
      w + (size_t)j * N_PTS + seg * 8192);
  const float4* sv = reinterpret_cast<const float4*>(sumw + seg * 8192);
  float s = 0.0f;
  #pragma unroll
  for (int q = 0; q < 8; ++q) {
    const int e = q * 256 + tid;
    float4 a = wj[e];
    float4 b = sv[e];
    s += a.x * (1.0f / b.x) + a.y * (1.0f / b.y) +
         a.z * (1.0f / b.z) + a.w * (1.0f / b.w);
  }
  #pragma unroll
  for (int off = 32; off > 0; off >>= 1) s += __shfl_down(s, off);
  if ((tid & 63) == 0) red[tid >> 6] = s;
  __syncthreads();
  if (tid == 0)
    atomicAdd(&fill_acc[j], red[0] + red[1] + red[2] + red[3]);
}

// stable member-list build, two-phase (1 barrier); the last-finishing block
// additionally computes offc/ord (byte-identical to the old k_offsets).
__global__ __launch_bounds__(1024) void k_scatter(
    const int* __restrict__ pred_x, const int* __restrict__ pred_t,
    int* __restrict__ idx_x, int* __restrict__ idx_t,
    int* __restrict__ count_x, int* __restrict__ count_t,
    int* __restrict__ done, int* __restrict__ offc, int* __restrict__ ord)
{
  const int c    = blockIdx.x >> 1;
  const int side = blockIdx.x & 1;
  const int* __restrict__ pred = side ? pred_t : pred_x;
  int* __restrict__ out = side ? idx_t : idx_x;
  int* __restrict__ cnt = side ? count_t : count_x;

  __shared__ int wsum[16];
  __shared__ int isLast;
  __shared__ int sm[128];
  __shared__ int mm[128];
  const int tid = threadIdx.x, lane = tid & 63, w = tid >> 6;
  const int beg = w * 4096;

  int cw = 0;
  for (int s = 0; s < 4096; s += 64) {
    const bool m = (pred[beg + s + lane] == c);
    cw += __popcll(__ballot(m));
  }
  if (lane == 0) wsum[w] = cw;
  __syncthreads();
  int base = 0, tot = 0;
  #pragma unroll
  for (int k = 0; k < 16; ++k) { int v = wsum[k]; tot += v; if (k < w) base += v; }

  int run = base;
  for (int s = 0; s < 4096; s += 64) {
    const int i = beg + s + lane;
    const bool m = (pred[i] == c);
    unsigned long long bal = __ballot(m);
    int lp = __popcll(bal & ((1ull << lane) - 1ull));
    if (m) { int pos = run + lp; if (pos < CAP) out[c * CAP + pos] = i; }
    run += __popcll(bal);
  }
  if (tid == 0) {
    cnt[c] = tot;
    __threadfence();                                  // release counts
    if (atomicAdd(done, 1) == 2 * K_CL - 1) {
      __threadfence();                                // acquire others'
      isLast = 1;
    } else {
      isLast = 0;
    }
  }
  __syncthreads();
  if (!isLast) return;

  // ---- offsets/ord (exact k_offsets logic; 128 active, all in barriers)
  int m0 = 0, sz0 = 0;
  if (tid < 128) {
    m0  = min(min(count_x[tid], CAP), min(count_t[tid], CAP));
    sz0 = ((m0 + 3) & ~3) * DIM;
    sm[tid] = sz0;
    mm[tid] = m0;
  }
  __syncthreads();
  if (tid < 128) {
    int rank = 0;
    for (int jj = 0; jj < 128; ++jj) {
      const int mj = mm[jj];
      if (mj > m0 || (mj == m0 && jj < tid)) ++rank;
    }
    ord[rank] = tid;
  }
  for (int s = 1; s < 128; s <<= 1) {
    int v = 0;
    if (tid < 128 && tid >= s) v = sm[tid - s];
    __syncthreads();
    if (tid < 128) sm[tid] += v;
    __syncthreads();
  }
  if (tid < 128) offc[tid] = sm[tid] - sz0;
}

// ---- in-register bitonic helpers ----
__device__ __forceinline__ void ce(float& a, float& b, bool up) {
  float lo = fminf(a, b), hi = fmaxf(a, b);
  a = up ? lo : hi;
  b = up ? hi : lo;
}

__device__ __forceinline__ void merge8(float* v, bool up) {
  ce(v[0],v[4],up); ce(v[1],v[5],up); ce(v[2],v[6],up); ce(v[3],v[7],up);
  ce(v[0],v[2],up); ce(v[1],v[3],up); ce(v[4],v[6],up); ce(v[5],v[7],up);
  ce(v[0],v[1],up); ce(v[2],v[3],up); ce(v[4],v[5],up); ce(v[6],v[7],up);
}

__device__ __forceinline__ void sort8(float* v, bool up8) {
  ce(v[0],v[1],true );  ce(v[2],v[3],false); ce(v[4],v[5],true );  ce(v[6],v[7],false);
  ce(v[0],v[2],true );  ce(v[1],v[3],true );  ce(v[4],v[6],false); ce(v[5],v[7],false);
  ce(v[0],v[1],true );  ce(v[2],v[3],true );  ce(v[4],v[5],false); ce(v[6],v[7],false);
  merge8(v, up8);
}

__device__ __forceinline__ void merge16(float* v, bool up) {
  #pragma unroll
  for (int e = 0; e < 8; ++e) ce(v[e], v[e + 8], up);
  merge8(v, up);
  merge8(v + 8, up);
}

__device__ __forceinline__ void sort16(float* v, bool up16) {
  sort8(v, true);
  sort8(v + 8, false);
  merge16(v, up16);
}

// branch min/max (R19: compiler likely if-converts; kept, measured-best)
__device__ __forceinline__ void stage_one8(float v[8], int ib, int k, bool up) {
  for (int j = (k >> 1) > 256 ? 256 : (k >> 1); j >= 8; j >>= 1) {
    const int  jl = j >> 3;
    const bool tm = (up == ((ib & j) == 0));
    float p[8];
    #pragma unroll
    for (int e = 0; e < 8; ++e) p[e] = __shfl_xor(v[e], jl, 64);
    if (tm) {
      #pragma unroll
      for (int e = 0; e < 8; ++e) v[e] = fminf(v[e], p[e]);
    } else {
      #pragma unroll
      for (int e = 0; e < 8; ++e) v[e] = fmaxf(v[e], p[e]);
    }
  }
  merge8(v, up);
}

__device__ __forceinline__ void stage_one16(float v[16], int ib, int k, bool up) {
  #pragma unroll
  for (int j = (k >> 1) > 512 ? 512 : (k >> 1); j >= 16; j >>= 1) {
    const int  jl = j >> 4;
    const bool tm = (up == ((ib & j) == 0));
    float p[16];
    #pragma unroll
    for (int e = 0; e < 16; ++e) p[e] = __shfl_xor(v[e], jl, 64);
    if (tm) {
      #pragma unroll
      for (int e = 0; e < 16; ++e) v[e] = fminf(v[e], p[e]);
    } else {
      #pragma unroll
      for (int e = 0; e < 16; ++e) v[e] = fmaxf(v[e], p[e]);
    }
  }
  merge16(v, up);
}

// gather loads: column (c,d) element r lives at src[idx[c*CAP+r]*DIM + d].
// idx reads are contiguous (vectorizable); the src gathers hit L2/L3 after
// the first d-task of a cluster touches its rows.
__device__ __forceinline__ void gather8(const float* __restrict__ src,
                                        const int* __restrict__ idxc,
                                        int d, int ib, int m, float v[8]) {
  #pragma unroll
  for (int e = 0; e < 8; ++e) {
    const int r = ib + e;
    v[e] = (r < m) ? src[(size_t)idxc[r] * DIM + d] : INFINITY;
  }
}

__device__ __forceinline__ void gather16(const float* __restrict__ src,
                                         const int* __restrict__ idxc,
                                         int d, int ib, int m, float v[16]) {
  #pragma unroll
  for (int e = 0; e < 16; ++e) {
    const int r = ib + e;
    v[e] = (r < m) ? src[(size_t)idxc[r] * DIM + d] : INFINITY;
  }
}

// XOR bank swizzle for the LDS exchange arena (R15: 3.58M conflict cycles
// unswizzled -> R16/R17: ~400K). Involution applied identically on w+r.
__device__ __forceinline__ int swz4(int fi) {
  return fi ^ (((fi >> 5) & 7) << 2);
}

// full P-sort of one gathered column; LDS only for j>=1024
template<int P>
__device__ __forceinline__ void sort_col(float v[16], int ib, bool act,
                                         const float* __restrict__ src,
                                         const int* __restrict__ idxc,
                                         int d, int m, float* __restrict__ sa) {
  if (act) {
    gather16(src, idxc, d, ib, m, v);
    sort16(v, ((ib & 16) == 0));
    #pragma unroll
    for (int k = 32; k <= 1024; k <<= 1)
      stage_one16(v, ib, k, ((ib & k) == 0));
  }
  #pragma unroll
  for (int k = 2048; k <= P; k <<= 1) {
    const bool up = ((ib & k) == 0);
    #pragma unroll
    for (int j = k >> 1; j >= 1024; j >>= 1) {
      __syncthreads();
      if (act) {
        #pragma unroll
        for (int q = 0; q < 4; ++q)
          *(float4*)&sa[swz4(ib + 4*q)] =
              make_float4(v[4*q], v[4*q+1], v[4*q+2], v[4*q+3]);
      }
      __syncthreads();
      if (act) {
        const int pi = ib ^ j;
        const bool tm = (up == ((ib & j) == 0));
        float A[16];
        #pragma unroll
        for (int q = 0; q < 4; ++q) {
          float4 f = *(const float4*)&sa[swz4(pi + 4*q)];
          A[4*q+0]=f.x; A[4*q+1]=f.y; A[4*q+2]=f.z; A[4*q+3]=f.w;
        }
        if (tm) {
          #pragma unroll
          for (int e = 0; e < 16; ++e) v[e] = fminf(v[e], A[e]);
        } else {
          #pragma unroll
          for (int e = 0; e < 16; ++e) v[e] = fmaxf(v[e], A[e]);
        }
      }
    }
    if (act) stage_one16(v, ib, k, up);
  }
}

template<int P>
__device__ __forceinline__ void sort_col_io(const float* __restrict__ src,
                                            const int* __restrict__ idxc,
                                            int d, float* __restrict__ col,
                                            int m, int mp, int tid,
                                            float* __restrict__ sa) {
  const int ib = tid << 4;
  const bool act = (ib < P);
  float v[16];
  sort_col<P>(v, ib, act, src, idxc, d, m, sa);
  if (act) {
    #pragma unroll
    for (int q = 0; q < 4; ++q)
      if (ib + 4 * q < mp)
        *(float4*)&col[ib + 4*q] =
            make_float4(v[4*q], v[4*q+1], v[4*q+2], v[4*q+3]);
  }
}

// Gather+sort fused (R24): each task pulls its column straight from x/t via
// idx and writes the SORTED column to gxT/gtT for k_diff. R19-frozen task
// structure: blocks [0,16384) one (side,c,d) LDS task (m>1024, heavy-first
// via ord); blocks [16384,18432) 8 independent wave-columns (m<=1024).
__global__ __launch_bounds__(512) void k_sort(
    const float* __restrict__ x, const float* __restrict__ t,
    const int* __restrict__ idx_x, const int* __restrict__ idx_t,
    float* __restrict__ gxT, float* __restrict__ gtT,
    const int* __restrict__ offc,
    const int* __restrict__ count_x, const int* __restrict__ count_t,
    const int* __restrict__ ord)
{
  __shared__ float sa[8192];   // 32 KB (task role only)
  const int tid = threadIdx.x;

  if (blockIdx.x < 16384) {
    const int side = blockIdx.x >> 13;
    const int cd   = blockIdx.x & 8191;
    const int c = ord[cd >> 6], d = cd & 63;
    const int m = min(min(count_x[c], CAP), min(count_t[c], CAP));
    if (m <= 1024) return;
    const int mp = (m + 3) & ~3;
    const float* src  = side ? t : x;
    const int*   idxc = (side ? idx_t : idx_x) + c * CAP;
    float* col = (side ? gtT : gxT) + offc[c] + (size_t)d * mp;
    if (m <= 2048)      sort_col_io<2048>(src, idxc, d, col, m, mp, tid, sa);
    else if (m <= 4096) sort_col_io<4096>(src, idxc, d, col, m, mp, tid, sa);
    else                sort_col_io<8192>(src, idxc, d, col, m, mp, tid, sa);
  } else {
    const int base = (blockIdx.x - 16384) * 8 + (tid >> 6);
    const int lane = tid & 63;
    const int side = base >> 13;
    const int cd   = base & 8191;
    const int c = ord[cd >> 6], d = cd & 63;
    const int m = min(min(count_x[c], CAP), min(count_t[c], CAP));
    if (m > 1024 || m == 0) return;
    const int mp = (m + 3) & ~3;
    const float* src  = side ? t : x;
    const int*   idxc = (side ? idx_t : idx_x) + c * CAP;
    float* col = (side ? gtT : gxT) + offc[c] + (size_t)d * mp;

    if (m <= 512) {
      int P = 8;
      while (P < m) P <<= 1;
      const int ib = lane << 3;
      float v[8];
      gather8(src, idxc, d, ib, m, v);
      sort8(v, ((ib & 8) == 0));
      for (int k = 16; k <= P; k <<= 1)        // runtime bound: spill-safe
        stage_one8(v, ib, k, ((ib & k) == 0));
      #pragma unroll
      for (int q = 0; q < 2; ++q)
        if (ib + 4 * q < mp)
          *(float4*)&col[ib + 4*q] =
              make_float4(v[4*q], v[4*q+1], v[4*q+2], v[4*q+3]);
    } else {
      const int ib = lane << 4;
      float v[16];
      gather16(src, idxc, d, ib, m, v);
      sort16(v, ((ib & 16) == 0));
      #pragma unroll
      for (int k = 32; k <= 1024; k <<= 1)
        stage_one16(v, ib, k, ((ib & k) == 0));
      #pragma unroll
      for (int q = 0; q < 4; ++q)
        if (ib + 4 * q < mp)
          *(float4*)&col[ib + 4*q] =
              make_float4(v[4*q], v[4*q+1], v[4*q+2], v[4*q+3]);
    }
  }
}

// streaming |sorted(a)-sorted(b)| reduce per (c,d); covers m==0 slots too
__global__ __launch_bounds__(256) void k_diff(
    const float* __restrict__ gxT, const float* __restrict__ gtT,
    const int* __restrict__ offc,
    const int* __restrict__ count_x, const int* __restrict__ count_t,
    float* __restrict__ parts)
{
  __shared__ float red[4];
  const int task = blockIdx.x;
  const int c = task >> 6, d = task & 63;
  const int m = min(min(count_x[c], CAP), min(count_t[c], CAP));
  const int tid = threadIdx.x;
  if (m == 0) { if (tid == 0) parts[task] = 0.0f; return; }
  const int mp = (m + 3) & ~3;
  const float* colx = gxT + offc[c] + (size_t)d * mp;
  const float* colt = gtT + offc[c] + (size_t)d * mp;
  float s = 0.0f;
  for (int r = tid * 4; r < mp; r += 1024) {
    float4 a = *(const float4*)&colx[r];
    float4 b = *(const float4*)&colt[r];
    if (r + 3 < m) {
      s += fabsf(a.x-b.x) + fabsf(a.y-b.y) + fabsf(a.z-b.z) + fabsf(a.w-b.w);
    } else {
      if (r + 0 < m) s += fabsf(a.x - b.x);
      if (r + 1 < m) s += fabsf(a.y - b.y);
      if (r + 2 < m) s += fabsf(a.z - b.z);
      if (r + 3 < m) s += fabsf(a.w - b.w);
    }
  }
  #pragma unroll
  for (int off = 32; off > 0; off >>= 1) s += __shfl_down(s, off);
  if ((tid & 63) == 0) red[tid >> 6] = s;
  __syncthreads();
  if (tid == 0)
    parts[task] = (red[0] + red[1] + red[2] + red[3]) / (float)(m * DIM);
}

__global__ __launch_bounds__(1024) void k_final(
    const float* __restrict__ fill_acc, const float* __restrict__ ft,
    const float* __restrict__ parts, float* __restrict__ out)
{
  __shared__ float red[16];
  const int tid = threadIdx.x;
  float s = 0.0f;
  #pragma unroll
  for (int i = 0; i < 8; ++i) s += parts[tid + i * 1024];
  if (tid < K_CL) {
    float v = fill_acc[tid] * (1.0f / (float)N_PTS) - ft[tid];
    s += v * v * (1.0f / (float)K_CL);
  }
  #pragma unroll
  for (int off = 32; off > 0; off >>= 1) s += __shfl_down(s, off);
  if ((tid & 63) == 0) red[tid >> 6] = s;
  __syncthreads();
  if (tid == 0) {
    float tot = 0.0f;
    #pragma unroll
    for (int w = 0; w < 16; ++w) tot += red[w];
    out[0] = tot;
  }
}

extern "C" void kernel_launch(void* const* d_in, const int* in_sizes, int n_in,
                              void* d_out, int out_size, void* d_ws, size_t ws_size,
                              hipStream_t stream)
{
  (void)in_sizes; (void)n_in; (void)out_size; (void)ws_size;
  const float* x      = (const float*)d_in[0];
  const float* target = (const float*)d_in[1];
  const float* cc     = (const float*)d_in[2];
  const int*   pred_t = (const int*)d_in[3];
  const float* ft     = (const float*)d_in[4];
  float* out = (float*)d_out;

  char* ws = (char*)d_ws;
  float* fill_acc = (float*)(ws + 0);
  int*   pred_x   = (int*)(ws + 1024);
  int*   idx_x    = (int*)(ws + 263168);
  int*   idx_t    = (int*)(ws + 4457472);
  int*   count_x  = (int*)(ws + 8651776);
  int*   count_t  = (int*)(ws + 8651776 + 512);
  float* parts    = (float*)(ws + 8652800);
  float* sumw     = (float*)(ws + 8685568);
  int*   done     = (int*)(ws + 8947712);
  unsigned long long* pred_enc = (unsigned long long*)(ws + 9209856);
  int*   offc     = (int*)(ws + 9734144);
  int*   ord      = (int*)(ws + 9734656);
  float* gxT      = (float*)(ws + 9735168);
  float* gtT      = (float*)(ws + 26643456);
  float* wmat     = (float*)(ws + 9735168);   // 32 MB, dead after k_fill;
                                              // overlays gxT+gtT only

  k_init<<<N_PTS / 256, 256, 0, stream>>>(fill_acc, sumw, pred_enc, done);
  k_dist1<<<N_PTS / 256 * 4, 256, 0, stream>>>(x, cc, sumw, pred_enc, wmat);
  k_fill<<<K_CL * 8, 256, 0, stream>>>(wmat, sumw, pred_enc, pred_x,
                                       fill_acc);
  k_scatter<<<K_CL * 2, 1024, 0, stream>>>(pred_x, pred_t, idx_x, idx_t,
                                           count_x, count_t, done, offc, ord);
  k_sort<<<16384 + 2048, 512, 0, stream>>>(x, target, idx_x, idx_t,
                                           gxT, gtT, offc,
                                           count_x, count_t, ord);
  k_diff<<<K_CL * DIM, 256, 0, stream>>>(gxT, gtT, offc,
                                         count_x, count_t, parts);
  k_final<<<1, 1024, 0, stream>>>(fill_acc, ft, parts, out);
}

// Round 14
// 283.316 us; speedup vs baseline: 1.0238x; 1.0238x over previous
//
#include <hip/hip_runtime.h>
#include <math.h>

#define N_PTS 65536
#define DIM   64
#define K_CL  128
#define EPSV  1e-8f
#define CAP   8192

// ---------------- ws layout (bytes) ----------------
// 0        : fill_acc[128] float
// 1024     : pred_x[N] int            -> 263168
// 263168   : idx_x[128*CAP] int       -> 4457472
// 4457472  : idx_t[128*CAP] int       -> 8651776
// 8651776  : count_x[128], +512: count_t[128]
// 8652800  : parts[8192] float        -> 8685568
// 8685568  : sumw[N] float            -> 8947712
// 8947712  : inv_sumw[N] float        -> 9209856
// 9209856  : pred_enc[N] u64          -> 9734144
// 9734144  : offc[128] int            -> 9734656
// 9734656  : ord[128] int             -> 9735168  (cluster ids, m desc)
// 9735168  : gxT (16908288 B)         -> 26643456   } wmat (32 MB, dead after
// 26643456 : gtT (16908288 B)         -> 43551744   } k_fill) overlays these
// FINAL (R24 structure, session best 284.07/284.57us; baseline was 322.8).
// Ledger: R19 heavy-first ord WIN; R24 gather-fused k_sort WIN (deleted
// k_gather_t). Refuted with counters: column packing (R16), 32/lane
// repartition (R18), diff fusion x3 (R20/R21), front-end fusion (R23,
// occupancy collapse), XCD binding +/- LPT (R25/R26: k_sort gain = k_diff
// L2-thrash loss), launch consolidation (R28: +6us). k_sort floor =
// invariant ~74us VALU issue (constant across R15-R26) on serial shfl
// dependency chains at ~51% efficiency vs scattered-gather latency --
// a latency local optimum; exit requires a different sort algorithm.

__global__ __launch_bounds__(256) void k_init(
    float* __restrict__ fill_acc, float* __restrict__ sumw,
    unsigned long long* __restrict__ pred_enc) {
  const int i = blockIdx.x * 256 + threadIdx.x;
  if (i < K_CL) fill_acc[i] = 0.0f;
  sumw[i] = 0.0f;
  pred_enc[i] = 0xFFFFFFFFFFFFFFFFull;
}

// Block-level K-split; jbase block-uniform -> centers scalarized (s_load).
// Writes w[j][p] (coalesced) so the normalize pass needn't recompute.
__global__ __launch_bounds__(256) void k_dist1(
    const float* __restrict__ x, const float* __restrict__ centers,
    float* __restrict__ sumw, unsigned long long* __restrict__ pred_enc,
    float* __restrict__ w)
{
  __shared__ float csq[32];
  const int kb    = blockIdx.x & 3;
  const int pb    = blockIdx.x >> 2;
  const int jbase = kb << 5;
  const int tid   = threadIdx.x;
  const int p     = pb * 256 + tid;

  if (tid < 32) {
    const float* cp = centers + (jbase + tid) * DIM;
    float s = 0.0f;
    #pragma unroll 8
    for (int d = 0; d < DIM; ++d) { float v = cp[d]; s += v * v; }
    csq[tid] = s;
  }

  float xr[DIM];
  const float4* xp = reinterpret_cast<const float4*>(x + (size_t)p * DIM);
  #pragma unroll
  for (int q = 0; q < DIM / 4; ++q) {
    float4 v = xp[q];
    xr[4 * q + 0] = v.x; xr[4 * q + 1] = v.y;
    xr[4 * q + 2] = v.z; xr[4 * q + 3] = v.w;
  }
  float xsq = 0.0f;
  #pragma unroll
  for (int d = 0; d < DIM; ++d) xsq += xr[d] * xr[d];
  __syncthreads();

  float sw = 0.0f, best = INFINITY;
  int   bj = jbase;
  #pragma unroll 2
  for (int jj = 0; jj < 32; ++jj) {
    const int j = jbase + jj;
    const float* cp = centers + j * DIM;
    float d0 = 0.f, d1 = 0.f, d2a = 0.f, d3 = 0.f;
    #pragma unroll
    for (int d = 0; d < DIM; d += 4) {
      d0  += xr[d + 0] * cp[d + 0];
      d1  += xr[d + 1] * cp[d + 1];
      d2a += xr[d + 2] * cp[d + 2];
      d3  += xr[d + 3] * cp[d + 3];
    }
    float dot  = (d0 + d1) + (d2a + d3);
    float dsq  = xsq + csq[jj] - 2.0f * dot;
    float dist = sqrtf(fmaxf(dsq, 0.0f));
    float ww   = 1.0f / (dist + EPSV);
    w[(size_t)j * N_PTS + p] = ww;
    sw += ww;
    if (dist < best) { best = dist; bj = j; }
  }
  atomicAdd(&sumw[p], sw);
  const unsigned long long enc =
      ((unsigned long long)__float_as_uint(best) << 32) | (unsigned int)bj;
  atomicMin(&pred_enc[p], enc);
}

__global__ __launch_bounds__(256) void k_pred(
    const unsigned long long* __restrict__ pred_enc,
    const float* __restrict__ sumw,
    int* __restrict__ pred_x, float* __restrict__ inv_sumw) {
  const int p = blockIdx.x * 256 + threadIdx.x;
  pred_x[p]   = (int)(pred_enc[p] & 0xFFFFFFFFull);
  inv_sumw[p] = 1.0f / sumw[p];
}

// streaming normalize+reduce: block (j, seg of 8192 points); 1 atomic/block
__global__ __launch_bounds__(256) void k_fill(
    const float* __restrict__ w, const float* __restrict__ inv_sumw,
    float* __restrict__ fill_acc)
{
  __shared__ float red[4];
  const int j    = blockIdx.x >> 3;
  const int seg  = blockIdx.x & 7;
  const int tid  = threadIdx.x;
  const float4* wj = reinterpret_cast<const float4*>(
      w + (size_t)j * N_PTS + seg * 8192);
  const float4* iv = reinterpret_cast<const float4*>(inv_sumw + seg * 8192);
  float s = 0.0f;
  #pragma unroll
  for (int q = 0; q < 8; ++q) {
    const int e = q * 256 + tid;
    float4 a = wj[e];
    float4 b = iv[e];
    s += a.x * b.x + a.y * b.y + a.z * b.z + a.w * b.w;
  }
  #pragma unroll
  for (int off = 32; off > 0; off >>= 1) s += __shfl_down(s, off);
  if ((tid & 63) == 0) red[tid >> 6] = s;
  __syncthreads();
  if (tid == 0)
    atomicAdd(&fill_acc[j], red[0] + red[1] + red[2] + red[3]);
}

// stable member-list build, two-phase (1 barrier)
__global__ __launch_bounds__(1024) void k_scatter(
    const int* __restrict__ pred_x, const int* __restrict__ pred_t,
    int* __restrict__ idx_x, int* __restrict__ idx_t,
    int* __restrict__ count_x, int* __restrict__ count_t)
{
  const int c    = blockIdx.x >> 1;
  const int side = blockIdx.x & 1;
  const int* __restrict__ pred = side ? pred_t : pred_x;
  int* __restrict__ out = side ? idx_t : idx_x;
  int* __restrict__ cnt = side ? count_t : count_x;

  __shared__ int wsum[16];
  const int tid = threadIdx.x, lane = tid & 63, w = tid >> 6;
  const int beg = w * 4096;

  int cw = 0;
  for (int s = 0; s < 4096; s += 64) {
    const bool m = (pred[beg + s + lane] == c);
    cw += __popcll(__ballot(m));
  }
  if (lane == 0) wsum[w] = cw;
  __syncthreads();
  int base = 0, tot = 0;
  #pragma unroll
  for (int k = 0; k < 16; ++k) { int v = wsum[k]; tot += v; if (k < w) base += v; }

  int run = base;
  for (int s = 0; s < 4096; s += 64) {
    const int i = beg + s + lane;
    const bool m = (pred[i] == c);
    unsigned long long bal = __ballot(m);
    int lp = __popcll(bal & ((1ull << lane) - 1ull));
    if (m) { int pos = run + lp; if (pos < CAP) out[c * CAP + pos] = i; }
    run += __popcll(bal);
  }
  if (tid == 0) cnt[c] = tot;
}

// offsets + heavy-first cluster order (rank by m desc, tie by id)
__global__ __launch_bounds__(128) void k_offsets(
    const int* __restrict__ count_x, const int* __restrict__ count_t,
    int* __restrict__ offc, int* __restrict__ ord)
{
  __shared__ int sm[128];
  __shared__ int mm[128];
  const int tid = threadIdx.x;
  const int m  = min(min(count_x[tid], CAP), min(count_t[tid], CAP));
  const int sz = ((m + 3) & ~3) * DIM;
  sm[tid] = sz;
  mm[tid] = m;
  __syncthreads();
  int rank = 0;
  for (int j = 0; j < 128; ++j) {
    const int mj = mm[j];
    if (mj > m || (mj == m && j < tid)) ++rank;
  }
  ord[rank] = tid;
  for (int s = 1; s < 128; s <<= 1) {
    int v = (tid >= s) ? sm[tid - s] : 0;
    __syncthreads();
    sm[tid] += v;
    __syncthreads();
  }
  offc[tid] = sm[tid] - sz;
}

// ---- in-register bitonic helpers ----
__device__ __forceinline__ void ce(float& a, float& b, bool up) {
  float lo = fminf(a, b), hi = fmaxf(a, b);
  a = up ? lo : hi;
  b = up ? hi : lo;
}

__device__ __forceinline__ void merge8(float* v, bool up) {
  ce(v[0],v[4],up); ce(v[1],v[5],up); ce(v[2],v[6],up); ce(v[3],v[7],up);
  ce(v[0],v[2],up); ce(v[1],v[3],up); ce(v[4],v[6],up); ce(v[5],v[7],up);
  ce(v[0],v[1],up); ce(v[2],v[3],up); ce(v[4],v[5],up); ce(v[6],v[7],up);
}

__device__ __forceinline__ void sort8(float* v, bool up8) {
  ce(v[0],v[1],true );  ce(v[2],v[3],false); ce(v[4],v[5],true );  ce(v[6],v[7],false);
  ce(v[0],v[2],true );  ce(v[1],v[3],true );  ce(v[4],v[6],false); ce(v[5],v[7],false);
  ce(v[0],v[1],true );  ce(v[2],v[3],true );  ce(v[4],v[5],false); ce(v[6],v[7],false);
  merge8(v, up8);
}

__device__ __forceinline__ void merge16(float* v, bool up) {
  #pragma unroll
  for (int e = 0; e < 8; ++e) ce(v[e], v[e + 8], up);
  merge8(v, up);
  merge8(v + 8, up);
}

__device__ __forceinline__ void sort16(float* v, bool up16) {
  sort8(v, true);
  sort8(v + 8, false);
  merge16(v, up16);
}

// branch min/max (R19: compiler likely if-converts; kept, measured-best)
__device__ __forceinline__ void stage_one8(float v[8], int ib, int k, bool up) {
  for (int j = (k >> 1) > 256 ? 256 : (k >> 1); j >= 8; j >>= 1) {
    const int  jl = j >> 3;
    const bool tm = (up == ((ib & j) == 0));
    float p[8];
    #pragma unroll
    for (int e = 0; e < 8; ++e) p[e] = __shfl_xor(v[e], jl, 64);
    if (tm) {
      #pragma unroll
      for (int e = 0; e < 8; ++e) v[e] = fminf(v[e], p[e]);
    } else {
      #pragma unroll
      for (int e = 0; e < 8; ++e) v[e] = fmaxf(v[e], p[e]);
    }
  }
  merge8(v, up);
}

__device__ __forceinline__ void stage_one16(float v[16], int ib, int k, bool up) {
  #pragma unroll
  for (int j = (k >> 1) > 512 ? 512 : (k >> 1); j >= 16; j >>= 1) {
    const int  jl = j >> 4;
    const bool tm = (up == ((ib & j) == 0));
    float p[16];
    #pragma unroll
    for (int e = 0; e < 16; ++e) p[e] = __shfl_xor(v[e], jl, 64);
    if (tm) {
      #pragma unroll
      for (int e = 0; e < 16; ++e) v[e] = fminf(v[e], p[e]);
    } else {
      #pragma unroll
      for (int e = 0; e < 16; ++e) v[e] = fmaxf(v[e], p[e]);
    }
  }
  merge16(v, up);
}

// gather loads: column (c,d) element r lives at src[idx[c*CAP+r]*DIM + d].
// idx reads are contiguous (vectorizable); the src gathers hit L2/L3 after
// the first d-task of a cluster touches its rows.
__device__ __forceinline__ void gather8(const float* __restrict__ src,
                                        const int* __restrict__ idxc,
                                        int d, int ib, int m, float v[8]) {
  #pragma unroll
  for (int e = 0; e < 8; ++e) {
    const int r = ib + e;
    v[e] = (r < m) ? src[(size_t)idxc[r] * DIM + d] : INFINITY;
  }
}

__device__ __forceinline__ void gather16(const float* __restrict__ src,
                                         const int* __restrict__ idxc,
                                         int d, int ib, int m, float v[16]) {
  #pragma unroll
  for (int e = 0; e < 16; ++e) {
    const int r = ib + e;
    v[e] = (r < m) ? src[(size_t)idxc[r] * DIM + d] : INFINITY;
  }
}

// XOR bank swizzle for the LDS exchange arena (R15: 3.58M conflict cycles
// unswizzled -> R16/R17: ~400K). Involution applied identically on w+r.
__device__ __forceinline__ int swz4(int fi) {
  return fi ^ (((fi >> 5) & 7) << 2);
}

// full P-sort of one gathered column; LDS only for j>=1024
template<int P>
__device__ __forceinline__ void sort_col(float v[16], int ib, bool act,
                                         const float* __restrict__ src,
                                         const int* __restrict__ idxc,
                                         int d, int m, float* __restrict__ sa) {
  if (act) {
    gather16(src, idxc, d, ib, m, v);
    sort16(v, ((ib & 16) == 0));
    #pragma unroll
    for (int k = 32; k <= 1024; k <<= 1)
      stage_one16(v, ib, k, ((ib & k) == 0));
  }
  #pragma unroll
  for (int k = 2048; k <= P; k <<= 1) {
    const bool up = ((ib & k) == 0);
    #pragma unroll
    for (int j = k >> 1; j >= 1024; j >>= 1) {
      __syncthreads();
      if (act) {
        #pragma unroll
        for (int q = 0; q < 4; ++q)
          *(float4*)&sa[swz4(ib + 4*q)] =
              make_float4(v[4*q], v[4*q+1], v[4*q+2], v[4*q+3]);
      }
      __syncthreads();
      if (act) {
        const int pi = ib ^ j;
        const bool tm = (up == ((ib & j) == 0));
        float A[16];
        #pragma unroll
        for (int q = 0; q < 4; ++q) {
          float4 f = *(const float4*)&sa[swz4(pi + 4*q)];
          A[4*q+0]=f.x; A[4*q+1]=f.y; A[4*q+2]=f.z; A[4*q+3]=f.w;
        }
        if (tm) {
          #pragma unroll
          for (int e = 0; e < 16; ++e) v[e] = fminf(v[e], A[e]);
        } else {
          #pragma unroll
          for (int e = 0; e < 16; ++e) v[e] = fmaxf(v[e], A[e]);
        }
      }
    }
    if (act) stage_one16(v, ib, k, up);
  }
}

template<int P>
__device__ __forceinline__ void sort_col_io(const float* __restrict__ src,
                                            const int* __restrict__ idxc,
                                            int d, float* __restrict__ col,
                                            int m, int mp, int tid,
                                            float* __restrict__ sa) {
  const int ib = tid << 4;
  const bool act = (ib < P);
  float v[16];
  sort_col<P>(v, ib, act, src, idxc, d, m, sa);
  if (act) {
    #pragma unroll
    for (int q = 0; q < 4; ++q)
      if (ib + 4 * q < mp)
        *(float4*)&col[ib + 4*q] =
            make_float4(v[4*q], v[4*q+1], v[4*q+2], v[4*q+3]);
  }
}

// Gather+sort fused (R24): each task pulls its column straight from x/t via
// idx and writes the SORTED column to gxT/gtT for k_diff. R19-frozen task
// structure: blocks [0,16384) one (side,c,d) LDS task (m>1024, heavy-first
// via ord); blocks [16384,18432) 8 independent wave-columns (m<=1024).
__global__ __launch_bounds__(512) void k_sort(
    const float* __restrict__ x, const float* __restrict__ t,
    const int* __restrict__ idx_x, const int* __restrict__ idx_t,
    float* __restrict__ gxT, float* __restrict__ gtT,
    const int* __restrict__ offc,
    const int* __restrict__ count_x, const int* __restrict__ count_t,
    const int* __restrict__ ord)
{
  __shared__ float sa[8192];   // 32 KB (task role only)
  const int tid = threadIdx.x;

  if (blockIdx.x < 16384) {
    const int side = blockIdx.x >> 13;
    const int cd   = blockIdx.x & 8191;
    const int c = ord[cd >> 6], d = cd & 63;
    const int m = min(min(count_x[c], CAP), min(count_t[c], CAP));
    if (m <= 1024) return;
    const int mp = (m + 3) & ~3;
    const float* src  = side ? t : x;
    const int*   idxc = (side ? idx_t : idx_x) + c * CAP;
    float* col = (side ? gtT : gxT) + offc[c] + (size_t)d * mp;
    if (m <= 2048)      sort_col_io<2048>(src, idxc, d, col, m, mp, tid, sa);
    else if (m <= 4096) sort_col_io<4096>(src, idxc, d, col, m, mp, tid, sa);
    else                sort_col_io<8192>(src, idxc, d, col, m, mp, tid, sa);
  } else {
    const int base = (blockIdx.x - 16384) * 8 + (tid >> 6);
    const int lane = tid & 63;
    const int side = base >> 13;
    const int cd   = base & 8191;
    const int c = ord[cd >> 6], d = cd & 63;
    const int m = min(min(count_x[c], CAP), min(count_t[c], CAP));
    if (m > 1024 || m == 0) return;
    const int mp = (m + 3) & ~3;
    const float* src  = side ? t : x;
    const int*   idxc = (side ? idx_t : idx_x) + c * CAP;
    float* col = (side ? gtT : gxT) + offc[c] + (size_t)d * mp;

    if (m <= 512) {
      int P = 8;
      while (P < m) P <<= 1;
      const int ib = lane << 3;
      float v[8];
      gather8(src, idxc, d, ib, m, v);
      sort8(v, ((ib & 8) == 0));
      for (int k = 16; k <= P; k <<= 1)        // runtime bound: spill-safe
        stage_one8(v, ib, k, ((ib & k) == 0));
      #pragma unroll
      for (int q = 0; q < 2; ++q)
        if (ib + 4 * q < mp)
          *(float4*)&col[ib + 4*q] =
              make_float4(v[4*q], v[4*q+1], v[4*q+2], v[4*q+3]);
    } else {
      const int ib = lane << 4;
      float v[16];
      gather16(src, idxc, d, ib, m, v);
      sort16(v, ((ib & 16) == 0));
      #pragma unroll
      for (int k = 32; k <= 1024; k <<= 1)
        stage_one16(v, ib, k, ((ib & k) == 0));
      #pragma unroll
      for (int q = 0; q < 4; ++q)
        if (ib + 4 * q < mp)
          *(float4*)&col[ib + 4*q] =
              make_float4(v[4*q], v[4*q+1], v[4*q+2], v[4*q+3]);
    }
  }
}

// streaming |sorted(a)-sorted(b)| reduce per (c,d); covers m==0 slots too
__global__ __launch_bounds__(256) void k_diff(
    const float* __restrict__ gxT, const float* __restrict__ gtT,
    const int* __restrict__ offc,
    const int* __restrict__ count_x, const int* __restrict__ count_t,
    float* __restrict__ parts)
{
  __shared__ float red[4];
  const int task = blockIdx.x;
  const int c = task >> 6, d = task & 63;
  const int m = min(min(count_x[c], CAP), min(count_t[c], CAP));
  const int tid = threadIdx.x;
  if (m == 0) { if (tid == 0) parts[task] = 0.0f; return; }
  const int mp = (m + 3) & ~3;
  const float* colx = gxT + offc[c] + (size_t)d * mp;
  const float* colt = gtT + offc[c] + (size_t)d * mp;
  float s = 0.0f;
  for (int r = tid * 4; r < mp; r += 1024) {
    float4 a = *(const float4*)&colx[r];
    float4 b = *(const float4*)&colt[r];
    if (r + 3 < m) {
      s += fabsf(a.x-b.x) + fabsf(a.y-b.y) + fabsf(a.z-b.z) + fabsf(a.w-b.w);
    } else {
      if (r + 0 < m) s += fabsf(a.x - b.x);
      if (r + 1 < m) s += fabsf(a.y - b.y);
      if (r + 2 < m) s += fabsf(a.z - b.z);
      if (r + 3 < m) s += fabsf(a.w - b.w);
    }
  }
  #pragma unroll
  for (int off = 32; off > 0; off >>= 1) s += __shfl_down(s, off);
  if ((tid & 63) == 0) red[tid >> 6] = s;
  __syncthreads();
  if (tid == 0)
    parts[task] = (red[0] + red[1] + red[2] + red[3]) / (float)(m * DIM);
}

__global__ __launch_bounds__(1024) void k_final(
    const float* __restrict__ fill_acc, const float* __restrict__ ft,
    const float* __restrict__ parts, float* __restrict__ out)
{
  __shared__ float red[16];
  const int tid = threadIdx.x;
  float s = 0.0f;
  #pragma unroll
  for (int i = 0; i < 8; ++i) s += parts[tid + i * 1024];
  if (tid < K_CL) {
    float v = fill_acc[tid] * (1.0f / (float)N_PTS) - ft[tid];
    s += v * v * (1.0f / (float)K_CL);
  }
  #pragma unroll
  for (int off = 32; off > 0; off >>= 1) s += __shfl_down(s, off);
  if ((tid & 63) == 0) red[tid >> 6] = s;
  __syncthreads();
  if (tid == 0) {
    float tot = 0.0f;
    #pragma unroll
    for (int w = 0; w < 16; ++w) tot += red[w];
    out[0] = tot;
  }
}

extern "C" void kernel_launch(void* const* d_in, const int* in_sizes, int n_in,
                              void* d_out, int out_size, void* d_ws, size_t ws_size,
                              hipStream_t stream)
{
  (void)in_sizes; (void)n_in; (void)out_size; (void)ws_size;
  const float* x      = (const float*)d_in[0];
  const float* target = (const float*)d_in[1];
  const float* cc     = (const float*)d_in[2];
  const int*   pred_t = (const int*)d_in[3];
  const float* ft     = (const float*)d_in[4];
  float* out = (float*)d_out;

  char* ws = (char*)d_ws;
  float* fill_acc = (float*)(ws + 0);
  int*   pred_x   = (int*)(ws + 1024);
  int*   idx_x    = (int*)(ws + 263168);
  int*   idx_t    = (int*)(ws + 4457472);
  int*   count_x  = (int*)(ws + 8651776);
  int*   count_t  = (int*)(ws + 8651776 + 512);
  float* parts    = (float*)(ws + 8652800);
  float* sumw     = (float*)(ws + 8685568);
  float* inv_sumw = (float*)(ws + 8947712);
  unsigned long long* pred_enc = (unsigned long long*)(ws + 9209856);
  int*   offc     = (int*)(ws + 9734144);
  int*   ord      = (int*)(ws + 9734656);
  float* gxT      = (float*)(ws + 9735168);
  float* gtT      = (float*)(ws + 26643456);
  float* wmat     = (float*)(ws + 9735168);   // 32 MB, dead after k_fill;
                                              // overlays gxT+gtT only

  k_init<<<N_PTS / 256, 256, 0, stream>>>(fill_acc, sumw, pred_enc);
  k_dist1<<<N_PTS / 256 * 4, 256, 0, stream>>>(x, cc, sumw, pred_enc, wmat);
  k_pred<<<N_PTS / 256, 256, 0, stream>>>(pred_enc, sumw, pred_x, inv_sumw);
  k_fill<<<K_CL * 8, 256, 0, stream>>>(wmat, inv_sumw, fill_acc);
  k_scatter<<<K_CL * 2, 1024, 0, stream>>>(pred_x, pred_t, idx_x, idx_t,
                                           count_x, count_t);
  k_offsets<<<1, 128, 0, stream>>>(count_x, count_t, offc, ord);
  k_sort<<<16384 + 2048, 512, 0, stream>>>(x, target, idx_x, idx_t,
                                           gxT, gtT, offc,
                                           count_x, count_t, ord);
  k_diff<<<K_CL * DIM, 256, 0, stream>>>(gxT, gtT, offc,
                                         count_x, count_t, parts);
  k_final<<<1, 1024, 0, stream>>>(fill_acc, ft, parts, out);
}